// Round 12
// baseline (18.155 us; speedup 1.0000x reference)
//
#include <hip/hip_runtime.h>
#include <hip/hip_bf16.h>
#include <math.h>

// Steerable CNP target prediction — separable RBF + bf16 MFMA.
//
// out[t,c] = (sum_i Kx[t,i] * V[t,c,i]) / (Sx[t]*Sy[t]),
//   V[t,c,i] = sum_j Ky[t,j] * FMc[j,i]   <- GEMM: mfma_f32_16x16x32_bf16
//
// Round 12: ALL exp work moved to the prep kernel (64 pack blocks + 256
// K-table blocks). prep writes: bfB (B-frags, bf16), aT (Ky A-frags, bf16,
// per 16-target block), KxT fp32 [NT][128], SxT/SyT fp32 (exact denoms).
// Main kernel: pure load->MFMA->reduce, one barrier for Kx LDS staging.
// Lessons kept: named regs only (r1), no forced occupancy (r3), VGPR<128
// (r4), packed coalesced B (r10), prefetch-before-use (r11).

#define NA      128
#define TT      16
#define THREADS 512

typedef __attribute__((ext_vector_type(8))) short short8;
typedef __attribute__((ext_vector_type(4))) float f32x4;

__device__ __forceinline__ short f2bf(float x) {
    __hip_bfloat16 h = __float2bfloat16(x);
    return *reinterpret_cast<short*>(&h);
}

// ---------------- prep kernel ----------------
// blocks [0,64): bfB pack:  bfB[(((c*8+n)*4+s)*64+L)*8+e] = FMc[k][i],
//                k=s*32+((L>>4)&3)*8+e, i=n*16+(L&15)   (softplus on c>=2)
// blocks [64,64+nb32): K tables for 32 targets each:
//                KxT[t][j], aT A-frag pack of Ky, SxT/SyT exact fp32 sums.
__global__ __launch_bounds__(256)
void prep(const float* __restrict__ fm, const float* __restrict__ grid,
          const float* __restrict__ xt, const float* __restrict__ lsp,
          short* __restrict__ bfB, short* __restrict__ aT,
          float* __restrict__ KxT, float* __restrict__ SxT,
          float* __restrict__ SyT, int n_target)
{
    const int tid = threadIdx.x;

    if (blockIdx.x < 64) {                       // ---- bfB pack ----
        const int idx = blockIdx.x * 256 + tid;  // 16384 = 4c x 128k x 32 i4
        const int c  = idx >> 12;
        const int k  = (idx >> 5) & 127;
        const int i0 = (idx & 31) * 4;
        float4 v = *reinterpret_cast<const float4*>(fm + c * NA * NA + k * NA + i0);
        if (c >= 2) {
            v.x = (v.x > 15.0f) ? v.x : log1pf(__expf(v.x));
            v.y = (v.y > 15.0f) ? v.y : log1pf(__expf(v.y));
            v.z = (v.z > 15.0f) ? v.z : log1pf(__expf(v.z));
            v.w = (v.w > 15.0f) ? v.w : log1pf(__expf(v.w));
        }
        const int s  = k >> 5;
        const int e  = k & 7;
        const int Lk = ((k >> 3) & 3) * 16;
        const float vv[4] = {v.x, v.y, v.z, v.w};
#pragma unroll
        for (int d = 0; d < 4; ++d) {
            const int i = i0 + d;
            const int n = i >> 4;
            const int L = Lk + (i & 15);
            bfB[(((c * 8 + n) * 4 + s) * 64 + L) * 8 + e] = f2bf(vv[d]);
        }
        return;
    }

    // ---- K tables: 32 targets per block, 8 lanes per target ----
    const int t0   = (blockIdx.x - 64) * 32;
    const int tloc = tid >> 3;        // 0..31
    const int jg   = tid & 7;         // j-group (16 j's each)
    const int t    = t0 + tloc;
    int tg = t; if (tg >= n_target) tg = n_target - 1;
    const float x0 = xt[tg * 2 + 0];
    const float x1 = xt[tg * 2 + 1];
    const float l      = lsp[0];
    const float inv2l2 = 0.5f / (l * l);
    const int bA   = t >> 4;          // 16-target block index for aT
    const int mloc = t & 15;

    float sx = 0.f, sy = 0.f;
#pragma unroll
    for (int q = 0; q < 4; ++q) {
        float kx0, kx1, kx2, kx3;
#define KPT(D, KX)                                                             \
        {                                                                      \
            const int j = jg * 16 + q * 4 + (D);                               \
            const float ax = grid[j * 2 + 1];   /* ax[j] = grid[j*2+1] */      \
            const float dx = x0 - ax, dy = x1 - ax;                            \
            KX = __expf(-dx * dx * inv2l2);                                    \
            const float ky = __expf(-dy * dy * inv2l2);                        \
            sx += KX; sy += ky;                                                \
            aT[((bA * 4 + (j >> 5)) * 64 + ((j & 31) >> 3) * 16 + mloc) * 8    \
               + (j & 7)] = f2bf(ky);                                          \
        }
        KPT(0, kx0) KPT(1, kx1) KPT(2, kx2) KPT(3, kx3)
#undef KPT
        const float4 o = {kx0, kx1, kx2, kx3};
        *reinterpret_cast<float4*>(&KxT[t * NA + jg * 16 + q * 4]) = o;
    }
    // reduce the 8 j-groups (lanes with equal t are adjacent: strides 1,2,4)
    sx += __shfl_xor(sx, 1); sy += __shfl_xor(sy, 1);
    sx += __shfl_xor(sx, 2); sy += __shfl_xor(sy, 2);
    sx += __shfl_xor(sx, 4); sy += __shfl_xor(sy, 4);
    if (jg == 0) { SxT[t] = sx; SyT[t] = sy; }
}

// ---------------- main kernel ----------------
__global__ __launch_bounds__(THREADS)
void cnp_mfma(const short* __restrict__ bfB,   // [4][8][4][64][8] bf16
              const short* __restrict__ aT,    // [nb16][4][64][8] bf16
              const float* __restrict__ KxT,   // [NTp][NA]
              const float* __restrict__ SxT, const float* __restrict__ SyT,
              float* __restrict__ out, int n_target)
{
    __shared__ __attribute__((aligned(16))) float Kx[TT * NA];   // 8 KB
    __shared__ float red[4][2][TT];

    const int tid  = threadIdx.x;
    const int wid  = tid >> 6;
    const int c    = wid & 3;         // channel
    const int nh   = wid >> 2;        // n-half
    const int lane = tid & 63;
    const int t0   = blockIdx.x * TT;

    // ---- B-frag prefetch ----
    const short8* bbase = reinterpret_cast<const short8*>(bfB)
                        + c * 2048 + nh * 4 * 256 + lane;
    const short8 b00 = bbase[0],         b01 = bbase[64],
                 b02 = bbase[128],       b03 = bbase[192];
    const short8 b10 = bbase[256],       b11 = bbase[256 + 64],
                 b12 = bbase[256 + 128], b13 = bbase[256 + 192];
    const short8 b20 = bbase[512],       b21 = bbase[512 + 64],
                 b22 = bbase[512 + 128], b23 = bbase[512 + 192];
    const short8 b30 = bbase[768],       b31 = bbase[768 + 64],
                 b32 = bbase[768 + 128], b33 = bbase[768 + 192];

    // ---- A-frag prefetch (pre-packed by prep) ----
    const short8* abase = reinterpret_cast<const short8*>(aT)
                        + blockIdx.x * 256 + lane;
    const short8 a0 = abase[0], a1 = abase[64], a2 = abase[128], a3 = abase[192];

    // ---- Kx staging: 1 float4 per thread -> LDS ----
    {
        const float4 kq = *reinterpret_cast<const float4*>(&KxT[t0 * NA + tid * 4]);
        *reinterpret_cast<float4*>(&Kx[tid * 4]) = kq;
    }
    __syncthreads();

    // ---- MFMA + stage-2 ----
    const int icol = lane & 15;
    const int tb   = (lane >> 4) * 4;
    f32x4 p = {0.f, 0.f, 0.f, 0.f};

#define NTILE(NN, B0, B1, B2, B3)                                              \
    {                                                                          \
        f32x4 acc = {0.f, 0.f, 0.f, 0.f};                                      \
        acc = __builtin_amdgcn_mfma_f32_16x16x32_bf16(a0, B0, acc, 0, 0, 0);   \
        acc = __builtin_amdgcn_mfma_f32_16x16x32_bf16(a1, B1, acc, 0, 0, 0);   \
        acc = __builtin_amdgcn_mfma_f32_16x16x32_bf16(a2, B2, acc, 0, 0, 0);   \
        acc = __builtin_amdgcn_mfma_f32_16x16x32_bf16(a3, B3, acc, 0, 0, 0);   \
        const int i = (nh * 4 + (NN)) * 16 + icol;                             \
        p.x = fmaf(Kx[(tb + 0) * NA + i], acc.x, p.x);                         \
        p.y = fmaf(Kx[(tb + 1) * NA + i], acc.y, p.y);                         \
        p.z = fmaf(Kx[(tb + 2) * NA + i], acc.z, p.z);                         \
        p.w = fmaf(Kx[(tb + 3) * NA + i], acc.w, p.w);                         \
    }
    NTILE(0, b00, b01, b02, b03)
    NTILE(1, b10, b11, b12, b13)
    NTILE(2, b20, b21, b22, b23)
    NTILE(3, b30, b31, b32, b33)
#undef NTILE

    // reduce over the 16 i-lanes (strides 1,2,4,8)
#pragma unroll
    for (int st = 1; st <= 8; st <<= 1) {
        p.x += __shfl_xor(p.x, st);
        p.y += __shfl_xor(p.y, st);
        p.z += __shfl_xor(p.z, st);
        p.w += __shfl_xor(p.w, st);
    }
    if ((lane & 15) == 0) {
        red[c][nh][tb + 0] = p.x;
        red[c][nh][tb + 1] = p.y;
        red[c][nh][tb + 2] = p.z;
        red[c][nh][tb + 3] = p.w;
    }
    __syncthreads();

    // ---- epilogue: combine n-halves, normalize, write (64 outputs) ----
    if (tid < 4 * TT) {
        const int t  = tid & (TT - 1);
        const int cc = tid >> 4;            // requires TT == 16
        const int tg = t0 + t;
        if (tg < n_target) {
            const float numer = red[cc][0][t] + red[cc][1][t];
            const float val = numer / (SxT[tg] * SyT[tg]);
            if (cc < 2) out[tg * 2 + cc] = val;                        // means
            else        out[n_target * 2 + tg * 2 + (cc - 2)] = val;   // sigmas
        }
    }
}

extern "C" void kernel_launch(void* const* d_in, const int* in_sizes, int n_in,
                              void* d_out, int out_size, void* d_ws, size_t ws_size,
                              hipStream_t stream) {
    const float* fm   = (const float*)d_in[0];
    const float* grid = (const float*)d_in[1];
    const float* xt   = (const float*)d_in[2];
    const float* lsp  = (const float*)d_in[3];
    float* out = (float*)d_out;

    const int n_target = in_sizes[2] / 2;                   // 8192
    const int nb32 = (n_target + 31) / 32;                  // 256 K-table blocks
    const int nb16 = (n_target + 15) / 16;                  // 512 main blocks
    const int NTp  = nb32 * 32;                             // padded targets

    // ---- ws partition (all 16B-aligned) ----
    char* w = (char*)d_ws;
    short* bfB = (short*)w;                      w += (size_t)65536 * 2;        // 128 KB
    short* aT  = (short*)w;                      w += (size_t)nb16 * 2048 * 2;  // 2 MB
    float* KxT = (float*)w;                      w += (size_t)NTp * NA * 4;     // 4 MB
    float* SxT = (float*)w;                      w += (size_t)NTp * 4;
    float* SyT = (float*)w;

    hipLaunchKernelGGL(prep, dim3(64 + nb32), dim3(256), 0, stream,
                       fm, grid, xt, lsp, bfB, aT, KxT, SxT, SyT, n_target);
    hipLaunchKernelGGL(cnp_mfma, dim3(nb16), dim3(THREADS), 0, stream,
                       bfB, aT, KxT, SxT, SyT, out, n_target);
}

// Round 13
// 16.027 us; speedup vs baseline: 1.1328x; 1.1328x over previous
//
#include <hip/hip_runtime.h>
#include <hip/hip_bf16.h>
#include <math.h>

// Steerable CNP target prediction — separable RBF + bf16 MFMA.
//
// out[t,c] = (sum_i Kx[t,i] * V[t,c,i]) / (Sx[t]*Sy[t]),
//   V[t,c,i] = sum_j Ky[t,j] * FMc[j,i]   <- GEMM: mfma_f32_16x16x32_bf16
//
// Round 13 = r11 minus ALL pre-MFMA LDS/barrier: Ky A-frags and stage-2 Kx
// are computed per-wave in registers (48 exps/lane, trans-pipe, hides the
// B prefetch latency); Sx/Sy via in-register tree + shuffle reduces. The
// only barrier left is the epilogue exchange. r12 lesson: recompute cheap
// exps, never materialize tables. r10 lesson: B stays packed+coalesced.

#define NA      128
#define TT      16
#define THREADS 512

typedef __attribute__((ext_vector_type(8))) short short8;
typedef __attribute__((ext_vector_type(4))) float f32x4;

__device__ __forceinline__ short f2bf(float x) {
    __hip_bfloat16 h = __float2bfloat16(x);
    return *reinterpret_cast<short*>(&h);
}

// ---------- pre-kernel: FM -> softplus'd bf16 fragment-linear layout ----------
// bfB[(((c*8+n)*4+s)*64+L)*8+e] = FMc[k][i], k=s*32+((L>>4)&3)*8+e, i=n*16+(L&15)
__global__ __launch_bounds__(256)
void pack_pre(const float* __restrict__ fm, short* __restrict__ bfB)
{
    const int idx = blockIdx.x * 256 + threadIdx.x;   // 16384 = 4c x 128k x 32 i4
    const int c  = idx >> 12;
    const int k  = (idx >> 5) & 127;
    const int i0 = (idx & 31) * 4;

    float4 v = *reinterpret_cast<const float4*>(fm + c * NA * NA + k * NA + i0);
    if (c >= 2) {
        v.x = (v.x > 15.0f) ? v.x : log1pf(__expf(v.x));
        v.y = (v.y > 15.0f) ? v.y : log1pf(__expf(v.y));
        v.z = (v.z > 15.0f) ? v.z : log1pf(__expf(v.z));
        v.w = (v.w > 15.0f) ? v.w : log1pf(__expf(v.w));
    }
    const int s  = k >> 5;
    const int e  = k & 7;
    const int Lk = ((k >> 3) & 3) * 16;
    const float vv[4] = {v.x, v.y, v.z, v.w};
#pragma unroll
    for (int d = 0; d < 4; ++d) {
        const int i = i0 + d;
        const int n = i >> 4;
        const int L = Lk + (i & 15);
        bfB[(((c * 8 + n) * 4 + s) * 64 + L) * 8 + e] = f2bf(vv[d]);
    }
}

// ---------- main kernel ----------
__global__ __launch_bounds__(THREADS)
void cnp_mfma(const short* __restrict__ bfB,   // [4][8][4][64][8] bf16
              const float* __restrict__ grid,  // [NA*NA][2]
              const float* __restrict__ xt,    // [T][2]
              const float* __restrict__ lsp,   // [1]
              float* __restrict__ out,         // means [T][2] then sigmas [T][2]
              int n_target)
{
    __shared__ float red[4][2][TT];
    __shared__ float psx[TT][2];
    __shared__ float psy[TT];

    const int tid  = threadIdx.x;
    const int wid  = tid >> 6;
    const int c    = wid & 3;         // channel
    const int nh   = wid >> 2;        // n-half
    const int lane = tid & 63;
    const int g    = lane >> 4;       // frag row-group
    const int m    = lane & 15;       // frag m / i-col
    const int t0   = blockIdx.x * TT;

    // ---- B-frag prefetch (issued first; latency hides under the exps) ----
    const short8* bbase = reinterpret_cast<const short8*>(bfB)
                        + c * 2048 + nh * 1024 + lane;
    const short8 b00 = bbase[0],         b01 = bbase[64],
                 b02 = bbase[128],       b03 = bbase[192];
    const short8 b10 = bbase[256],       b11 = bbase[256 + 64],
                 b12 = bbase[256 + 128], b13 = bbase[256 + 192];
    const short8 b20 = bbase[512],       b21 = bbase[512 + 64],
                 b22 = bbase[512 + 128], b23 = bbase[512 + 192];
    const short8 b30 = bbase[768],       b31 = bbase[768 + 64],
                 b32 = bbase[768 + 128], b33 = bbase[768 + 192];

    const float l      = lsp[0];
    const float inv2l2 = 0.5f / (l * l);

    // ---- Ky A-frags in registers + Sy partial (32 exps/lane) ----
    // lane holds Ky[t0+m][j = s*32 + g*8 + e]; ax[j] = grid[j*2+1]
    int tgm = t0 + m; if (tgm >= n_target) tgm = n_target - 1;
    const float ty = xt[tgm * 2 + 1];
    float syp = 0.0f;
    short8 a0, a1, a2, a3;
#define AFRAG(AS, S)                                                           \
    {                                                                          \
        short8 av;                                                             \
        _Pragma("unroll")                                                      \
        for (int e = 0; e < 8; ++e) {                                          \
            const int j = (S) * 32 + g * 8 + e;                                \
            const float axv = grid[j * 2 + 1];                                 \
            const float d   = ty - axv;                                        \
            const float kv  = __expf(-d * d * inv2l2);                         \
            syp += kv;                                                         \
            av[e] = f2bf(kv);                                                  \
        }                                                                      \
        AS = av;                                                               \
    }
    AFRAG(a0, 0) AFRAG(a1, 1) AFRAG(a2, 2) AFRAG(a3, 3)
#undef AFRAG
    // complete Sy[t0+m] across the 4 g-groups
    syp += __shfl_xor(syp, 16);
    syp += __shfl_xor(syp, 32);
    if (wid == 0 && lane < 16) psy[lane] = syp;

    // ---- stage-2 Kx in registers (16 exps/lane) ----
    // C/D map: col=m -> i, row = g*4 + reg  ->  t = t0 + g*4 + r
    const int tb = g * 4;
    int tr0 = t0 + tb + 0; if (tr0 >= n_target) tr0 = n_target - 1;
    int tr1 = t0 + tb + 1; if (tr1 >= n_target) tr1 = n_target - 1;
    int tr2 = t0 + tb + 2; if (tr2 >= n_target) tr2 = n_target - 1;
    int tr3 = t0 + tb + 3; if (tr3 >= n_target) tr3 = n_target - 1;
    const float tx0 = xt[tr0 * 2], tx1 = xt[tr1 * 2],
                tx2 = xt[tr2 * 2], tx3 = xt[tr3 * 2];
    const float axi0 = grid[(((nh * 4 + 0) * 16 + m) * 2) + 1];
    const float axi1 = grid[(((nh * 4 + 1) * 16 + m) * 2) + 1];
    const float axi2 = grid[(((nh * 4 + 2) * 16 + m) * 2) + 1];
    const float axi3 = grid[(((nh * 4 + 3) * 16 + m) * 2) + 1];
#define KXE(TX, AX) __expf(-((TX) - (AX)) * ((TX) - (AX)) * inv2l2)
    f32x4 kx0 = {KXE(tx0, axi0), KXE(tx1, axi0), KXE(tx2, axi0), KXE(tx3, axi0)};
    f32x4 kx1 = {KXE(tx0, axi1), KXE(tx1, axi1), KXE(tx2, axi1), KXE(tx3, axi1)};
    f32x4 kx2 = {KXE(tx0, axi2), KXE(tx1, axi2), KXE(tx2, axi2), KXE(tx3, axi2)};
    f32x4 kx3 = {KXE(tx0, axi3), KXE(tx1, axi3), KXE(tx2, axi3), KXE(tx3, axi3)};
#undef KXE

    // ---- MFMA + stage-2 dot (no barrier needed before this) ----
    f32x4 p = {0.f, 0.f, 0.f, 0.f};
#define NTILE(KX, B0, B1, B2, B3)                                              \
    {                                                                          \
        f32x4 acc = {0.f, 0.f, 0.f, 0.f};                                      \
        acc = __builtin_amdgcn_mfma_f32_16x16x32_bf16(a0, B0, acc, 0, 0, 0);   \
        acc = __builtin_amdgcn_mfma_f32_16x16x32_bf16(a1, B1, acc, 0, 0, 0);   \
        acc = __builtin_amdgcn_mfma_f32_16x16x32_bf16(a2, B2, acc, 0, 0, 0);   \
        acc = __builtin_amdgcn_mfma_f32_16x16x32_bf16(a3, B3, acc, 0, 0, 0);   \
        p.x = fmaf(KX.x, acc.x, p.x);                                          \
        p.y = fmaf(KX.y, acc.y, p.y);                                          \
        p.z = fmaf(KX.z, acc.z, p.z);                                          \
        p.w = fmaf(KX.w, acc.w, p.w);                                          \
    }
    NTILE(kx0, b00, b01, b02, b03)
    NTILE(kx1, b10, b11, b12, b13)
    NTILE(kx2, b20, b21, b22, b23)
    NTILE(kx3, b30, b31, b32, b33)
#undef NTILE

    // ---- reduce numer over the 16 i-lanes ----
#pragma unroll
    for (int st = 1; st <= 8; st <<= 1) {
        p.x += __shfl_xor(p.x, st);
        p.y += __shfl_xor(p.y, st);
        p.z += __shfl_xor(p.z, st);
        p.w += __shfl_xor(p.w, st);
    }
    if (m == 0) {
        red[c][nh][tb + 0] = p.x;
        red[c][nh][tb + 1] = p.y;
        red[c][nh][tb + 2] = p.z;
        red[c][nh][tb + 3] = p.w;
    }

    // ---- Sx partial from in-register Kx (c==0 waves only) ----
    if (c == 0) {
        f32x4 q;
        q.x = (kx0.x + kx1.x) + (kx2.x + kx3.x);
        q.y = (kx0.y + kx1.y) + (kx2.y + kx3.y);
        q.z = (kx0.z + kx1.z) + (kx2.z + kx3.z);
        q.w = (kx0.w + kx1.w) + (kx2.w + kx3.w);
#pragma unroll
        for (int st = 1; st <= 8; st <<= 1) {
            q.x += __shfl_xor(q.x, st);
            q.y += __shfl_xor(q.y, st);
            q.z += __shfl_xor(q.z, st);
            q.w += __shfl_xor(q.w, st);
        }
        if (m == 0) {
            psx[tb + 0][nh] = q.x;
            psx[tb + 1][nh] = q.y;
            psx[tb + 2][nh] = q.z;
            psx[tb + 3][nh] = q.w;
        }
    }
    __syncthreads();

    // ---- epilogue: combine n-halves, normalize, write (64 outputs) ----
    if (tid < 4 * TT) {
        const int t  = tid & (TT - 1);
        const int cc = tid >> 4;            // requires TT == 16
        const int tg = t0 + t;
        if (tg < n_target) {
            const float numer = red[cc][0][t] + red[cc][1][t];
            const float Sx = psx[t][0] + psx[t][1];
            const float val = numer / (Sx * psy[t]);
            if (cc < 2) out[tg * 2 + cc] = val;                        // means
            else        out[n_target * 2 + tg * 2 + (cc - 2)] = val;   // sigmas
        }
    }
}

extern "C" void kernel_launch(void* const* d_in, const int* in_sizes, int n_in,
                              void* d_out, int out_size, void* d_ws, size_t ws_size,
                              hipStream_t stream) {
    const float* fm   = (const float*)d_in[0];
    const float* grid = (const float*)d_in[1];
    const float* xt   = (const float*)d_in[2];
    const float* lsp  = (const float*)d_in[3];
    float* out = (float*)d_out;
    short* bfB = (short*)d_ws;                     // 4*8*4*64*8 bf16 = 128 KB

    const int n_target = in_sizes[2] / 2;          // 8192

    hipLaunchKernelGGL(pack_pre, dim3(64), dim3(256), 0, stream, fm, bfB);

    const int blocks = (n_target + TT - 1) / TT;   // 512
    hipLaunchKernelGGL(cnp_mfma, dim3(blocks), dim3(THREADS), 0, stream,
                       bfB, grid, xt, lsp, out, n_target);
}